// Round 7
// baseline (161.165 us; speedup 1.0000x reference)
//
#include <hip/hip_runtime.h>
#include <hip/hip_bf16.h>

// ---------------------------------------------------------------------------
// MHSA: x[2,2048,1024] f32, Wq/Wk/Wv/Wo[1024,1024] f32 -> out[2,2048,1024] f32.
// Internal bf16. Pipeline:
//   1) convert: x -> xb (bf16 in d_out[0:8MB]); W* -> wb (ws)
//   2) fused QKV GEMM (global_load_lds): Q,K row-major; V transposed VtG[1024][4096]
//   3) causal flash attention: 1 wave / 32 q-rows, NO LDS — K/V fragments read
//      directly from L2 (per-head K,V = 256KB each; 4 heads/XCD = 2MB < 4MB L2).
//      No barriers at all; all 2048 waves co-resident.
//   4) Wo GEMM -> f32 d_out
// ws (shorts): wb[4x1M] Q[4M] K[4M] VtG[4M] = 32 MB. attn out aliases Q.
// ---------------------------------------------------------------------------

#define DEVI __device__ __forceinline__

typedef __bf16 bf16x8 __attribute__((ext_vector_type(8)));
typedef short  short8 __attribute__((ext_vector_type(8)));
typedef float  f32x4  __attribute__((ext_vector_type(4)));
typedef float  f32x16 __attribute__((ext_vector_type(16)));
typedef unsigned int u32x4 __attribute__((ext_vector_type(4)));

DEVI short f2bfs(float f) {
    __hip_bfloat16 h = __float2bfloat16(f);
    return __builtin_bit_cast(short, h);
}
DEVI unsigned pack2(float a, float b) {
    return (unsigned)(unsigned short)f2bfs(a) | ((unsigned)(unsigned short)f2bfs(b) << 16);
}
DEVI bf16x8 ld8(const short* p) {
    return __builtin_bit_cast(bf16x8, *(const short8*)p);
}
DEVI void gload16(const void* g, void* lds) {
    __builtin_amdgcn_global_load_lds(
        (const __attribute__((address_space(1))) void*)g,
        (__attribute__((address_space(3))) void*)lds, 16, 0, 0);
}

#if defined(__has_builtin)
#if __has_builtin(__builtin_amdgcn_exp2f)
#define HAVE_EXP2 1
#endif
#endif
DEVI float ex2(float x) {
#ifdef HAVE_EXP2
    return __builtin_amdgcn_exp2f(x);
#else
    return __expf(x * 0.69314718055994531f);
#endif
}
// 0.125 (1/sqrt(64)) folded with log2(e): p = 2^((s - m) * CEXP)
#define CEXP 0.18033688011112042f

// ---------------------------------------------------------------------------
// f32 -> bf16 convert.  z=0: x (4M elems) -> xb; z=1..4: W* (1M) -> wb slots.
// ---------------------------------------------------------------------------
__global__ __launch_bounds__(256) void convert_kernel(
    const float* __restrict__ x, const float* __restrict__ Wq,
    const float* __restrict__ Wk, const float* __restrict__ Wv,
    const float* __restrict__ Wo, short* __restrict__ xb, short* __restrict__ wb) {
    const int z = blockIdx.y;
    const float* src;
    short* dst;
    int n;
    if (z == 0) { src = x; dst = xb; n = 4194304; }
    else {
        src = (z == 1) ? Wq : (z == 2) ? Wk : (z == 3) ? Wv : Wo;
        dst = wb + (size_t)(z - 1) * 1048576;
        n = 1048576;
    }
    const int i8 = (blockIdx.x * 256 + threadIdx.x) * 8;
    if (i8 >= n) return;
    float4 a = ((const float4*)(src + i8))[0];
    float4 b = ((const float4*)(src + i8))[1];
    short8 t;
    t[0] = f2bfs(a.x); t[1] = f2bfs(a.y); t[2] = f2bfs(a.z); t[3] = f2bfs(a.w);
    t[4] = f2bfs(b.x); t[5] = f2bfs(b.y); t[6] = f2bfs(b.z); t[7] = f2bfs(b.w);
    *(short8*)(dst + i8) = t;
}

// ---------------------------------------------------------------------------
// bf16 NT-GEMM K-loop (m97 structure): 128x128 tile, BK=32, global_load_lds.
// (unchanged — known good)
// ---------------------------------------------------------------------------
DEVI void gemm_kloop(const short* __restrict__ A, const short* __restrict__ B,
                     short* As, short* Bs, int wid, int lane, f32x4 acc[4][4]) {
    const int l15 = lane & 15, l4 = lane >> 4;
    const int wm = wid >> 1, wn = wid & 1;
    const int crow = lane >> 2;
    const int ccol = (lane & 3) * 8;
#pragma unroll 1
    for (int k0 = 0; k0 < 1024; k0 += 32) {
        __syncthreads();
#pragma unroll
        for (int i = 0; i < 2; ++i) {
            const int cb = wid * 2 + i;
            gload16(A + (size_t)(cb * 16 + crow) * 1024 + k0 + ccol, As + cb * 512);
            gload16(B + (size_t)(cb * 16 + crow) * 1024 + k0 + ccol, Bs + cb * 512);
        }
        __syncthreads();
        bf16x8 af[4], bfv[4];
#pragma unroll
        for (int m = 0; m < 4; ++m)
            af[m] = ld8(As + (wm * 64 + m * 16 + l15) * 32 + l4 * 8);
#pragma unroll
        for (int n = 0; n < 4; ++n)
            bfv[n] = ld8(Bs + (wn * 64 + n * 16 + l15) * 32 + l4 * 8);
#pragma unroll
        for (int m = 0; m < 4; ++m)
#pragma unroll
            for (int n = 0; n < 4; ++n)
                acc[m][n] = __builtin_amdgcn_mfma_f32_16x16x32_bf16(af[m], bfv[n], acc[m][n], 0, 0, 0);
    }
}

// ---------------------------------------------------------------------------
// Fused QKV projection. grid (32, 24): y>>3 selects weight; (y&7) col tile.
// ---------------------------------------------------------------------------
__global__ __launch_bounds__(256) void gemm_qkv_kernel(
    const short* __restrict__ xb, const short* __restrict__ wb,
    short* __restrict__ Qo, short* __restrict__ Ko, short* __restrict__ VtG) {
    __shared__ short As[4096], Bs[4096];
    const int tid = threadIdx.x, lane = tid & 63, wid = tid >> 6;
    const int l15 = lane & 15, l4 = lane >> 4;
    const int wm = wid >> 1, wn = wid & 1;
    const int y = blockIdx.y, wsel = y >> 3;
    const int row0 = blockIdx.x * 128, col0 = (y & 7) * 128;

    f32x4 acc[4][4] = {};
    gemm_kloop(xb + (size_t)row0 * 1024,
               wb + (size_t)wsel * 1048576 + (size_t)col0 * 1024,
               As, Bs, wid, lane, acc);

    if (wsel == 2) {
#pragma unroll
        for (int m = 0; m < 4; ++m)
#pragma unroll
            for (int n = 0; n < 4; ++n)
#pragma unroll
                for (int j = 0; j < 4; ++j) {
                    int row = row0 + wm * 64 + m * 16 + l4 * 4 + j;
                    int col = col0 + wn * 64 + n * 16 + l15;
                    VtG[(size_t)col * 4096 + row] = f2bfs(acc[m][n][j]);
                }
    } else {
        short* C = (wsel == 0) ? Qo : Ko;
#pragma unroll
        for (int m = 0; m < 4; ++m)
#pragma unroll
            for (int n = 0; n < 4; ++n)
#pragma unroll
                for (int j = 0; j < 4; ++j) {
                    int row = row0 + wm * 64 + m * 16 + l4 * 4 + j;
                    int col = col0 + wn * 64 + n * 16 + l15;
                    C[(size_t)row * 1024 + col] = f2bfs(acc[m][n][j]);
                }
    }
}

__global__ __launch_bounds__(256) void gemm_wo_kernel(
    const short* __restrict__ Ao, const short* __restrict__ Wob,
    float* __restrict__ Cout) {
    __shared__ short As[4096], Bs[4096];
    const int tid = threadIdx.x, lane = tid & 63, wid = tid >> 6;
    const int l15 = lane & 15, l4 = lane >> 4;
    const int wm = wid >> 1, wn = wid & 1;
    const int row0 = blockIdx.x * 128, col0 = blockIdx.y * 128;

    f32x4 acc[4][4] = {};
    gemm_kloop(Ao + (size_t)row0 * 1024, Wob + (size_t)col0 * 1024,
               As, Bs, wid, lane, acc);

#pragma unroll
    for (int m = 0; m < 4; ++m)
#pragma unroll
        for (int n = 0; n < 4; ++n)
#pragma unroll
            for (int j = 0; j < 4; ++j) {
                int row = row0 + wm * 64 + m * 16 + l4 * 4 + j;
                int col = col0 + wn * 64 + n * 16 + l15;
                Cout[(size_t)row * 1024 + col] = acc[m][n][j];
            }
}

// ---------------------------------------------------------------------------
// One KV tile, operands straight from global (L2-resident).
// Verified math (rounds 4-6): S = K Q^T (C[kv][q], 32x32x16), exp2-domain
// online softmax with defer-max, shfl_xor(32) P-redistribute, O += P V.
//   kRow0/kRow1: &K[l31][hi*8], &K[32+l31][hi*8]   (row stride 1024)
//   vRow0/vRow1: &Vt[l31][hi*8], &Vt[32+l31][hi*8] (row stride 4096)
// ---------------------------------------------------------------------------
DEVI void attn_tile_g(int kv0, bool diag,
                      const short* __restrict__ kRow0, const short* __restrict__ kRow1,
                      const short* __restrict__ vRow0, const short* __restrict__ vRow1,
                      const bf16x8 qf[4], f32x16& o0, f32x16& o1,
                      float& m, float& l, int qrow, int hi) {
    // ---- issue ALL 16 fragment loads up front (L2 hits, ~200cyc) ----
    bf16x8 kf[8], vb[8];
#pragma unroll
    for (int ds = 0; ds < 4; ++ds) {
        kf[ds]     = ld8(kRow0 + (size_t)kv0 * 1024 + ds * 16);
        kf[4 + ds] = ld8(kRow1 + (size_t)kv0 * 1024 + ds * 16);
    }
#pragma unroll
    for (int c = 0; c < 2; ++c) {
        vb[c * 4 + 0] = ld8(vRow0 + kv0 + c * 32);
        vb[c * 4 + 1] = ld8(vRow1 + kv0 + c * 32);
        vb[c * 4 + 2] = ld8(vRow0 + kv0 + c * 32 + 16);
        vb[c * 4 + 3] = ld8(vRow1 + kv0 + c * 32 + 16);
    }

    // ---- S = K Q^T ----
    f32x16 s0 = 0.0f, s1 = 0.0f;
    __builtin_amdgcn_s_setprio(1);
#pragma unroll
    for (int ds = 0; ds < 4; ++ds)
        s0 = __builtin_amdgcn_mfma_f32_32x32x16_bf16(kf[ds], qf[ds], s0, 0, 0, 0);
#pragma unroll
    for (int ds = 0; ds < 4; ++ds)
        s1 = __builtin_amdgcn_mfma_f32_32x32x16_bf16(kf[4 + ds], qf[ds], s1, 0, 0, 0);
    __builtin_amdgcn_s_setprio(0);

    if (diag) {
#pragma unroll
        for (int r = 0; r < 16; ++r) {
            const int kvr = kv0 + (r & 3) + 8 * (r >> 2) + 4 * hi;
            if (kvr > qrow)      s0[r] = -3.0e38f;
            if (kvr + 32 > qrow) s1[r] = -3.0e38f;
        }
    }
    float mx0 = -3.0e38f, mx1 = -3.0e38f, mx2 = -3.0e38f, mx3 = -3.0e38f;
#pragma unroll
    for (int r = 0; r < 16; r += 4) {
        mx0 = fmaxf(mx0, fmaxf(s0[r],     s1[r]));
        mx1 = fmaxf(mx1, fmaxf(s0[r + 1], s1[r + 1]));
        mx2 = fmaxf(mx2, fmaxf(s0[r + 2], s1[r + 2]));
        mx3 = fmaxf(mx3, fmaxf(s0[r + 3], s1[r + 3]));
    }
    float pmax = fmaxf(fmaxf(mx0, mx1), fmaxf(mx2, mx3));
    pmax = fmaxf(pmax, __shfl_xor(pmax, 32, 64));

    if (__any(pmax > m + 64.0f)) {
        const float mnew = fmaxf(m, pmax);
        const float corr = ex2((m - mnew) * CEXP);
        m = mnew;
        l *= corr;
#pragma unroll
        for (int r = 0; r < 16; ++r) {
            const int cr = (r & 3) + 8 * (r >> 2) + 4 * hi;
            const float c = __shfl(corr, cr, 64);
            o0[r] *= c; o1[r] *= c;
        }
    }

    const float mc = m * CEXP;
    float r0 = 0.f, r1 = 0.f, r2 = 0.f, r3 = 0.f;
    unsigned w0[8], w1[8];
#pragma unroll
    for (int i = 0; i < 8; ++i) {
        const float p0 = ex2(__builtin_fmaf(s0[2 * i],     CEXP, -mc));
        const float p1 = ex2(__builtin_fmaf(s0[2 * i + 1], CEXP, -mc));
        const float p2 = ex2(__builtin_fmaf(s1[2 * i],     CEXP, -mc));
        const float p3 = ex2(__builtin_fmaf(s1[2 * i + 1], CEXP, -mc));
        r0 += p0; r1 += p1; r2 += p2; r3 += p3;
        w0[i] = pack2(p0, p1);
        w1[i] = pack2(p2, p3);
    }
    const float rsum = (r0 + r1) + (r2 + r3);
    l += rsum + __shfl_xor(rsum, 32, 64);

    __builtin_amdgcn_s_setprio(1);
#pragma unroll
    for (int c = 0; c < 2; ++c) {
        const unsigned* w = (c == 0) ? w0 : w1;
        unsigned pw[8];
#pragma unroll
        for (int i = 0; i < 8; ++i) pw[i] = __shfl_xor(w[i], 32, 64);
        u32x4 lo, hw;
        lo[0] = hi ? pw[2] : w[0];  lo[1] = hi ? pw[3] : w[1];
        lo[2] = hi ? w[2]  : pw[0]; lo[3] = hi ? w[3]  : pw[1];
        hw[0] = hi ? pw[6] : w[4];  hw[1] = hi ? pw[7] : w[5];
        hw[2] = hi ? w[6]  : pw[4]; hw[3] = hi ? w[7]  : pw[5];
        const bf16x8 paL = __builtin_bit_cast(bf16x8, lo);
        const bf16x8 paH = __builtin_bit_cast(bf16x8, hw);

        o0 = __builtin_amdgcn_mfma_f32_32x32x16_bf16(paL, vb[c * 4 + 0], o0, 0, 0, 0);
        o1 = __builtin_amdgcn_mfma_f32_32x32x16_bf16(paL, vb[c * 4 + 1], o1, 0, 0, 0);
        o0 = __builtin_amdgcn_mfma_f32_32x32x16_bf16(paH, vb[c * 4 + 2], o0, 0, 0, 0);
        o1 = __builtin_amdgcn_mfma_f32_32x32x16_bf16(paH, vb[c * 4 + 3], o1, 0, 0, 0);
    }
    __builtin_amdgcn_s_setprio(0);
}

// ---------------------------------------------------------------------------
// Causal flash attention, LDS-free. grid 2048 x 64 threads (1 wave, 32 q-rows).
// qw = 63 - bid/32 (heavy-first within head), bh = bid&31 — with XCD
// round-robin (bid%8) each XCD touches only 4 heads -> K+V 2MB, L2-resident.
// All waves co-resident (no LDS, VGPR<256): no tail, no barriers.
// Exactly ONE diagonal (masked) tile per wave -> split out of the main loop.
// ---------------------------------------------------------------------------
__global__ __launch_bounds__(64) void attn_kernel(
    const short* __restrict__ Q, const short* __restrict__ K,
    const short* __restrict__ VtG, short* __restrict__ O) {
    const int lane = threadIdx.x & 63;
    const int l31 = lane & 31, hi = lane >> 5;
    const int bid = blockIdx.x;
    const int qw = 63 - (bid >> 5);     // 0..63 within head, heavy-first
    const int bh = bid & 31;
    const int b = bh >> 4, h = bh & 15;
    const size_t base = (size_t)b * 2048 * 1024 + (size_t)h * 64;
    const short* Qp = Q + base;
    const short* Kp = K + base;
    const short* Vp = VtG + (size_t)(h * 64) * 4096 + (size_t)b * 2048;
    short* Op = O + base;

    const int q0w = qw * 32;
    const int qrow = q0w + l31;

    bf16x8 qf[4];
#pragma unroll
    for (int ds = 0; ds < 4; ++ds)
        qf[ds] = ld8(Qp + (size_t)qrow * 1024 + ds * 16 + hi * 8);

    // per-lane fragment row bases
    const short* kRow0 = Kp + (size_t)l31 * 1024 + hi * 8;
    const short* kRow1 = Kp + (size_t)(32 + l31) * 1024 + hi * 8;
    const short* vRow0 = Vp + (size_t)l31 * 4096 + hi * 8;
    const short* vRow1 = Vp + (size_t)(32 + l31) * 4096 + hi * 8;

    f32x16 o0 = 0.0f, o1 = 0.0f;
    float m = -INFINITY, l = 0.0f;
    const int ntiles = q0w / 64 + 1;

#pragma unroll 1
    for (int t = 0; t < ntiles - 1; ++t)
        attn_tile_g(t * 64, false, kRow0, kRow1, vRow0, vRow1, qf, o0, o1, m, l, qrow, hi);
    attn_tile_g((ntiles - 1) * 64, true, kRow0, kRow1, vRow0, vRow1, qf, o0, o1, m, l, qrow, hi);

    const float il = 1.0f / l;
#pragma unroll
    for (int r = 0; r < 16; ++r) {
        const int cr = (r & 3) + 8 * (r >> 2) + 4 * hi;
        const float s = __shfl(il, cr, 64);
        const size_t row = (size_t)(q0w + cr) * 1024;
        Op[row + l31]      = f2bfs(o0[r] * s);
        Op[row + 32 + l31] = f2bfs(o1[r] * s);
    }
}

// ---------------------------------------------------------------------------
extern "C" void kernel_launch(void* const* d_in, const int* in_sizes, int n_in,
                              void* d_out, int out_size, void* d_ws, size_t ws_size,
                              hipStream_t stream) {
    const float* x  = (const float*)d_in[0];
    const float* Wq = (const float*)d_in[1];
    const float* Wk = (const float*)d_in[2];
    const float* Wv = (const float*)d_in[3];
    const float* Wo = (const float*)d_in[4];

    short* wb  = (short*)d_ws;                 // 4 x 1M shorts (8 MB)
    short* Qw  = wb + (size_t)4 * 1048576;     // 8 MB (attn out aliases this)
    short* Kw  = Qw + (size_t)4194304;         // 8 MB
    short* Vtw = Kw + (size_t)4194304;         // 8 MB  (VtG[1024][4096])
    short* xb  = (short*)d_out;                // bf16 x lives in d_out[0:8MB]

    convert_kernel<<<dim3(2048, 5), 256, 0, stream>>>(x, Wq, Wk, Wv, Wo, xb, wb);
    gemm_qkv_kernel<<<dim3(32, 24), 256, 0, stream>>>(xb, wb, Qw, Kw, Vtw);
    attn_kernel<<<2048, 64, 0, stream>>>(Qw, Kw, Vtw, Qw);
    gemm_wo_kernel<<<dim3(32, 8), 256, 0, stream>>>(Qw, wb + (size_t)3 * 1048576, (float*)d_out);
}

// Round 8
// 158.094 us; speedup vs baseline: 1.0194x; 1.0194x over previous
//
#include <hip/hip_runtime.h>
#include <hip/hip_bf16.h>

// ---------------------------------------------------------------------------
// MHSA: x[2,2048,1024] f32, Wq/Wk/Wv/Wo[1024,1024] f32 -> out[2,2048,1024] f32.
// Internal bf16. Pipeline:
//   1) convert: x -> xb (bf16 in d_out[0:8MB]); W* -> wb (ws)
//   2) fused QKV GEMM (global_load_lds): Q,K row-major; V transposed VtG[1024][4096]
//   3) causal flash attention: split-KV, 2 waves / 32 q-rows, no K/V staging
//      (per-XCD KV working set 2MB = L2-resident), LDS only for the final
//      flash-merge of the two waves' partial (m,l,O).
//   4) Wo GEMM -> f32 d_out
// ws (shorts): wb[4x1M] Q[4M] K[4M] VtG[4M] = 32 MB. attn out aliases Q.
// ---------------------------------------------------------------------------

#define DEVI __device__ __forceinline__

typedef __bf16 bf16x8 __attribute__((ext_vector_type(8)));
typedef short  short8 __attribute__((ext_vector_type(8)));
typedef float  f32x4  __attribute__((ext_vector_type(4)));
typedef float  f32x16 __attribute__((ext_vector_type(16)));
typedef unsigned int u32x4 __attribute__((ext_vector_type(4)));

DEVI short f2bfs(float f) {
    __hip_bfloat16 h = __float2bfloat16(f);
    return __builtin_bit_cast(short, h);
}
DEVI unsigned pack2(float a, float b) {
    return (unsigned)(unsigned short)f2bfs(a) | ((unsigned)(unsigned short)f2bfs(b) << 16);
}
DEVI bf16x8 ld8(const short* p) {
    return __builtin_bit_cast(bf16x8, *(const short8*)p);
}
DEVI void gload16(const void* g, void* lds) {
    __builtin_amdgcn_global_load_lds(
        (const __attribute__((address_space(1))) void*)g,
        (__attribute__((address_space(3))) void*)lds, 16, 0, 0);
}

#if defined(__has_builtin)
#if __has_builtin(__builtin_amdgcn_exp2f)
#define HAVE_EXP2 1
#endif
#endif
DEVI float ex2(float x) {
#ifdef HAVE_EXP2
    return __builtin_amdgcn_exp2f(x);
#else
    return __expf(x * 0.69314718055994531f);
#endif
}
// 0.125 (1/sqrt(64)) folded with log2(e): p = 2^((s - m) * CEXP)
#define CEXP 0.18033688011112042f

// ---------------------------------------------------------------------------
// f32 -> bf16 convert.  z=0: x (4M elems) -> xb; z=1..4: W* (1M) -> wb slots.
// ---------------------------------------------------------------------------
__global__ __launch_bounds__(256) void convert_kernel(
    const float* __restrict__ x, const float* __restrict__ Wq,
    const float* __restrict__ Wk, const float* __restrict__ Wv,
    const float* __restrict__ Wo, short* __restrict__ xb, short* __restrict__ wb) {
    const int z = blockIdx.y;
    const float* src;
    short* dst;
    int n;
    if (z == 0) { src = x; dst = xb; n = 4194304; }
    else {
        src = (z == 1) ? Wq : (z == 2) ? Wk : (z == 3) ? Wv : Wo;
        dst = wb + (size_t)(z - 1) * 1048576;
        n = 1048576;
    }
    const int i8 = (blockIdx.x * 256 + threadIdx.x) * 8;
    if (i8 >= n) return;
    float4 a = ((const float4*)(src + i8))[0];
    float4 b = ((const float4*)(src + i8))[1];
    short8 t;
    t[0] = f2bfs(a.x); t[1] = f2bfs(a.y); t[2] = f2bfs(a.z); t[3] = f2bfs(a.w);
    t[4] = f2bfs(b.x); t[5] = f2bfs(b.y); t[6] = f2bfs(b.z); t[7] = f2bfs(b.w);
    *(short8*)(dst + i8) = t;
}

// ---------------------------------------------------------------------------
// bf16 NT-GEMM K-loop (m97 structure): 128x128 tile, BK=32, global_load_lds.
// (unchanged — known good)
// ---------------------------------------------------------------------------
DEVI void gemm_kloop(const short* __restrict__ A, const short* __restrict__ B,
                     short* As, short* Bs, int wid, int lane, f32x4 acc[4][4]) {
    const int l15 = lane & 15, l4 = lane >> 4;
    const int wm = wid >> 1, wn = wid & 1;
    const int crow = lane >> 2;
    const int ccol = (lane & 3) * 8;
#pragma unroll 1
    for (int k0 = 0; k0 < 1024; k0 += 32) {
        __syncthreads();
#pragma unroll
        for (int i = 0; i < 2; ++i) {
            const int cb = wid * 2 + i;
            gload16(A + (size_t)(cb * 16 + crow) * 1024 + k0 + ccol, As + cb * 512);
            gload16(B + (size_t)(cb * 16 + crow) * 1024 + k0 + ccol, Bs + cb * 512);
        }
        __syncthreads();
        bf16x8 af[4], bfv[4];
#pragma unroll
        for (int m = 0; m < 4; ++m)
            af[m] = ld8(As + (wm * 64 + m * 16 + l15) * 32 + l4 * 8);
#pragma unroll
        for (int n = 0; n < 4; ++n)
            bfv[n] = ld8(Bs + (wn * 64 + n * 16 + l15) * 32 + l4 * 8);
#pragma unroll
        for (int m = 0; m < 4; ++m)
#pragma unroll
            for (int n = 0; n < 4; ++n)
                acc[m][n] = __builtin_amdgcn_mfma_f32_16x16x32_bf16(af[m], bfv[n], acc[m][n], 0, 0, 0);
    }
}

// ---------------------------------------------------------------------------
// Fused QKV projection. grid (32, 24): y>>3 selects weight; (y&7) col tile.
// ---------------------------------------------------------------------------
__global__ __launch_bounds__(256) void gemm_qkv_kernel(
    const short* __restrict__ xb, const short* __restrict__ wb,
    short* __restrict__ Qo, short* __restrict__ Ko, short* __restrict__ VtG) {
    __shared__ short As[4096], Bs[4096];
    const int tid = threadIdx.x, lane = tid & 63, wid = tid >> 6;
    const int l15 = lane & 15, l4 = lane >> 4;
    const int wm = wid >> 1, wn = wid & 1;
    const int y = blockIdx.y, wsel = y >> 3;
    const int row0 = blockIdx.x * 128, col0 = (y & 7) * 128;

    f32x4 acc[4][4] = {};
    gemm_kloop(xb + (size_t)row0 * 1024,
               wb + (size_t)wsel * 1048576 + (size_t)col0 * 1024,
               As, Bs, wid, lane, acc);

    if (wsel == 2) {
#pragma unroll
        for (int m = 0; m < 4; ++m)
#pragma unroll
            for (int n = 0; n < 4; ++n)
#pragma unroll
                for (int j = 0; j < 4; ++j) {
                    int row = row0 + wm * 64 + m * 16 + l4 * 4 + j;
                    int col = col0 + wn * 64 + n * 16 + l15;
                    VtG[(size_t)col * 4096 + row] = f2bfs(acc[m][n][j]);
                }
    } else {
        short* C = (wsel == 0) ? Qo : Ko;
#pragma unroll
        for (int m = 0; m < 4; ++m)
#pragma unroll
            for (int n = 0; n < 4; ++n)
#pragma unroll
                for (int j = 0; j < 4; ++j) {
                    int row = row0 + wm * 64 + m * 16 + l4 * 4 + j;
                    int col = col0 + wn * 64 + n * 16 + l15;
                    C[(size_t)row * 1024 + col] = f2bfs(acc[m][n][j]);
                }
    }
}

__global__ __launch_bounds__(256) void gemm_wo_kernel(
    const short* __restrict__ Ao, const short* __restrict__ Wob,
    float* __restrict__ Cout) {
    __shared__ short As[4096], Bs[4096];
    const int tid = threadIdx.x, lane = tid & 63, wid = tid >> 6;
    const int l15 = lane & 15, l4 = lane >> 4;
    const int wm = wid >> 1, wn = wid & 1;
    const int row0 = blockIdx.x * 128, col0 = blockIdx.y * 128;

    f32x4 acc[4][4] = {};
    gemm_kloop(Ao + (size_t)row0 * 1024, Wob + (size_t)col0 * 1024,
               As, Bs, wid, lane, acc);

#pragma unroll
    for (int m = 0; m < 4; ++m)
#pragma unroll
        for (int n = 0; n < 4; ++n)
#pragma unroll
            for (int j = 0; j < 4; ++j) {
                int row = row0 + wm * 64 + m * 16 + l4 * 4 + j;
                int col = col0 + wn * 64 + n * 16 + l15;
                Cout[(size_t)row * 1024 + col] = acc[m][n][j];
            }
}

// ---------------------------------------------------------------------------
// One KV tile, operands straight from global (L2-resident). Verified math
// (rounds 4-7): S = K Q^T (C[kv][q], 32x32x16), exp2-domain online softmax
// with defer-max, shfl_xor(32) P-redistribute, O += P V.
// ---------------------------------------------------------------------------
DEVI void attn_tile_g(int kv0, bool diag,
                      const short* __restrict__ kRow0, const short* __restrict__ kRow1,
                      const short* __restrict__ vRow0, const short* __restrict__ vRow1,
                      const bf16x8 qf[4], f32x16& o0, f32x16& o1,
                      float& m, float& l, int qrow, int hi) {
    bf16x8 kf[8], vb[8];
#pragma unroll
    for (int ds = 0; ds < 4; ++ds) {
        kf[ds]     = ld8(kRow0 + (size_t)kv0 * 1024 + ds * 16);
        kf[4 + ds] = ld8(kRow1 + (size_t)kv0 * 1024 + ds * 16);
    }
#pragma unroll
    for (int c = 0; c < 2; ++c) {
        vb[c * 4 + 0] = ld8(vRow0 + kv0 + c * 32);
        vb[c * 4 + 1] = ld8(vRow1 + kv0 + c * 32);
        vb[c * 4 + 2] = ld8(vRow0 + kv0 + c * 32 + 16);
        vb[c * 4 + 3] = ld8(vRow1 + kv0 + c * 32 + 16);
    }

    f32x16 s0 = 0.0f, s1 = 0.0f;
    __builtin_amdgcn_s_setprio(1);
#pragma unroll
    for (int ds = 0; ds < 4; ++ds)
        s0 = __builtin_amdgcn_mfma_f32_32x32x16_bf16(kf[ds], qf[ds], s0, 0, 0, 0);
#pragma unroll
    for (int ds = 0; ds < 4; ++ds)
        s1 = __builtin_amdgcn_mfma_f32_32x32x16_bf16(kf[4 + ds], qf[ds], s1, 0, 0, 0);
    __builtin_amdgcn_s_setprio(0);

    if (diag) {
#pragma unroll
        for (int r = 0; r < 16; ++r) {
            const int kvr = kv0 + (r & 3) + 8 * (r >> 2) + 4 * hi;
            if (kvr > qrow)      s0[r] = -3.0e38f;
            if (kvr + 32 > qrow) s1[r] = -3.0e38f;
        }
    }
    float mx0 = -3.0e38f, mx1 = -3.0e38f, mx2 = -3.0e38f, mx3 = -3.0e38f;
#pragma unroll
    for (int r = 0; r < 16; r += 4) {
        mx0 = fmaxf(mx0, fmaxf(s0[r],     s1[r]));
        mx1 = fmaxf(mx1, fmaxf(s0[r + 1], s1[r + 1]));
        mx2 = fmaxf(mx2, fmaxf(s0[r + 2], s1[r + 2]));
        mx3 = fmaxf(mx3, fmaxf(s0[r + 3], s1[r + 3]));
    }
    float pmax = fmaxf(fmaxf(mx0, mx1), fmaxf(mx2, mx3));
    pmax = fmaxf(pmax, __shfl_xor(pmax, 32, 64));

    if (__any(pmax > m + 64.0f)) {
        const float mnew = fmaxf(m, pmax);
        const float corr = ex2((m - mnew) * CEXP);
        m = mnew;
        l *= corr;
#pragma unroll
        for (int r = 0; r < 16; ++r) {
            const int cr = (r & 3) + 8 * (r >> 2) + 4 * hi;
            const float c = __shfl(corr, cr, 64);
            o0[r] *= c; o1[r] *= c;
        }
    }

    const float mc = m * CEXP;
    float r0 = 0.f, r1 = 0.f, r2 = 0.f, r3 = 0.f;
    unsigned w0[8], w1[8];
#pragma unroll
    for (int i = 0; i < 8; ++i) {
        const float p0 = ex2(__builtin_fmaf(s0[2 * i],     CEXP, -mc));
        const float p1 = ex2(__builtin_fmaf(s0[2 * i + 1], CEXP, -mc));
        const float p2 = ex2(__builtin_fmaf(s1[2 * i],     CEXP, -mc));
        const float p3 = ex2(__builtin_fmaf(s1[2 * i + 1], CEXP, -mc));
        r0 += p0; r1 += p1; r2 += p2; r3 += p3;
        w0[i] = pack2(p0, p1);
        w1[i] = pack2(p2, p3);
    }
    const float rsum = (r0 + r1) + (r2 + r3);
    l += rsum + __shfl_xor(rsum, 32, 64);

    __builtin_amdgcn_s_setprio(1);
#pragma unroll
    for (int c = 0; c < 2; ++c) {
        const unsigned* w = (c == 0) ? w0 : w1;
        unsigned pw[8];
#pragma unroll
        for (int i = 0; i < 8; ++i) pw[i] = __shfl_xor(w[i], 32, 64);
        u32x4 lo, hw;
        lo[0] = hi ? pw[2] : w[0];  lo[1] = hi ? pw[3] : w[1];
        lo[2] = hi ? w[2]  : pw[0]; lo[3] = hi ? w[3]  : pw[1];
        hw[0] = hi ? pw[6] : w[4];  hw[1] = hi ? pw[7] : w[5];
        hw[2] = hi ? w[6]  : pw[4]; hw[3] = hi ? w[7]  : pw[5];
        const bf16x8 paL = __builtin_bit_cast(bf16x8, lo);
        const bf16x8 paH = __builtin_bit_cast(bf16x8, hw);

        o0 = __builtin_amdgcn_mfma_f32_32x32x16_bf16(paL, vb[c * 4 + 0], o0, 0, 0, 0);
        o1 = __builtin_amdgcn_mfma_f32_32x32x16_bf16(paL, vb[c * 4 + 1], o1, 0, 0, 0);
        o0 = __builtin_amdgcn_mfma_f32_32x32x16_bf16(paH, vb[c * 4 + 2], o0, 0, 0, 0);
        o1 = __builtin_amdgcn_mfma_f32_32x32x16_bf16(paH, vb[c * 4 + 3], o1, 0, 0, 0);
    }
    __builtin_amdgcn_s_setprio(0);
}

// ---------------------------------------------------------------------------
// Causal flash attention, split-KV. grid 2048 x 128 (2 waves per block, SAME
// 32 q-rows; wave 0: kv tiles [0,nt/2), wave 1: [nt/2,nt) incl. the diagonal).
// 4096 waves total, ALL co-resident (VGPR<=128, LDS 9KB): max TLP, no staging.
// qw = 63-(bid>>5) heavy-first; bh = bid&31 -> 4 heads/XCD = 2MB KV in L2.
// Final flash-merge of the two partials via LDS.
// ---------------------------------------------------------------------------
__global__ __launch_bounds__(128) void attn_kernel(
    const short* __restrict__ Q, const short* __restrict__ K,
    const short* __restrict__ VtG, short* __restrict__ O) {
    __shared__ float Ms[64], Lsh[64];
    __shared__ float Osh[64][33];      // [lane][r]: r<16 -> o0, r>=16 -> o1

    const int tid = threadIdx.x, lane = tid & 63, wid = tid >> 6;
    const int l31 = lane & 31, hi = lane >> 5;
    const int bid = blockIdx.x;
    const int qw = 63 - (bid >> 5);     // 0..63, heavy-first
    const int bh = bid & 31;
    const int b = bh >> 4, h = bh & 15;
    const size_t base = (size_t)b * 2048 * 1024 + (size_t)h * 64;
    const short* Qp = Q + base;
    const short* Kp = K + base;
    const short* Vp = VtG + (size_t)(h * 64) * 4096 + (size_t)b * 2048;
    short* Op = O + base;

    const int q0w = qw * 32;
    const int qrow = q0w + l31;

    bf16x8 qf[4];
#pragma unroll
    for (int ds = 0; ds < 4; ++ds)
        qf[ds] = ld8(Qp + (size_t)qrow * 1024 + ds * 16 + hi * 8);

    const short* kRow0 = Kp + (size_t)l31 * 1024 + hi * 8;
    const short* kRow1 = Kp + (size_t)(32 + l31) * 1024 + hi * 8;
    const short* vRow0 = Vp + (size_t)l31 * 4096 + hi * 8;
    const short* vRow1 = Vp + (size_t)(32 + l31) * 4096 + hi * 8;

    f32x16 o0 = 0.0f, o1 = 0.0f;
    float m = -INFINITY, l = 0.0f;

    const int nt = ((q0w + 31) >> 6) + 1;   // total kv tiles for these rows
    const int hsp = nt >> 1;
    const int tA = wid ? hsp : 0;           // this wave's range [tA, tB)
    const int tB = wid ? nt : hsp;
    const int tU = wid ? (tB - 1) : tB;     // unmasked sub-range end

#pragma unroll 1
    for (int t = tA; t < tU; ++t)
        attn_tile_g(t * 64, false, kRow0, kRow1, vRow0, vRow1, qf, o0, o1, m, l, qrow, hi);
    if (wid)
        attn_tile_g((nt - 1) * 64, true, kRow0, kRow1, vRow0, vRow1, qf, o0, o1, m, l, qrow, hi);

    // ---- publish wave 1's partial, merge in wave 0 ----
    if (wid) {
        Ms[lane] = m;
        Lsh[lane] = l;
#pragma unroll
        for (int r = 0; r < 16; ++r) {
            Osh[lane][r]      = o0[r];
            Osh[lane][16 + r] = o1[r];
        }
    }
    __syncthreads();
    if (wid == 0) {
#pragma unroll
        for (int r = 0; r < 16; ++r) {
            const int cr = (r & 3) + 8 * (r >> 2) + 4 * hi;   // local q-row
            const float m0q = __shfl(m, cr, 64);
            const float l0q = __shfl(l, cr, 64);
            const float m1q = Ms[cr];
            const float l1q = Lsh[cr];
            const float M   = fmaxf(m0q, m1q);
            const float c0  = ex2((m0q - M) * CEXP);
            const float c1  = ex2((m1q - M) * CEXP);
            const float inv = 1.0f / (c0 * l0q + c1 * l1q);
            const float v0  = (c0 * o0[r] + c1 * Osh[lane][r])      * inv;
            const float v1  = (c0 * o1[r] + c1 * Osh[lane][16 + r]) * inv;
            const size_t row = (size_t)(q0w + cr) * 1024;
            Op[row + l31]      = f2bfs(v0);
            Op[row + 32 + l31] = f2bfs(v1);
        }
    }
}

// ---------------------------------------------------------------------------
extern "C" void kernel_launch(void* const* d_in, const int* in_sizes, int n_in,
                              void* d_out, int out_size, void* d_ws, size_t ws_size,
                              hipStream_t stream) {
    const float* x  = (const float*)d_in[0];
    const float* Wq = (const float*)d_in[1];
    const float* Wk = (const float*)d_in[2];
    const float* Wv = (const float*)d_in[3];
    const float* Wo = (const float*)d_in[4];

    short* wb  = (short*)d_ws;                 // 4 x 1M shorts (8 MB)
    short* Qw  = wb + (size_t)4 * 1048576;     // 8 MB (attn out aliases this)
    short* Kw  = Qw + (size_t)4194304;         // 8 MB
    short* Vtw = Kw + (size_t)4194304;         // 8 MB  (VtG[1024][4096])
    short* xb  = (short*)d_out;                // bf16 x lives in d_out[0:8MB]

    convert_kernel<<<dim3(2048, 5), 256, 0, stream>>>(x, Wq, Wk, Wv, Wo, xb, wb);
    gemm_qkv_kernel<<<dim3(32, 24), 256, 0, stream>>>(xb, wb, Qw, Kw, Vtw);
    attn_kernel<<<2048, 128, 0, stream>>>(Qw, Kw, Vtw, Qw);
    gemm_wo_kernel<<<dim3(32, 8), 256, 0, stream>>>(Qw, wb + (size_t)3 * 1048576, (float*)d_out);
}

// Round 9
// 127.246 us; speedup vs baseline: 1.2666x; 1.2424x over previous
//
#include <hip/hip_runtime.h>
#include <hip/hip_bf16.h>

// ---------------------------------------------------------------------------
// MHSA: x[2,2048,1024] f32, Wq/Wk/Wv/Wo[1024,1024] f32 -> out[2,2048,1024] f32.
// Internal bf16. Pipeline:
//   1) convert: x -> xb (bf16 in d_out[0:8MB]); W* -> wb (ws)
//   2) fused QKV GEMM: BK=64, XOR-swizzled global_load_lds staging (conflict-
//      free ds_read_b128), 16 K-steps. Q,K row-major; V transposed VtG.
//   3) causal flash attention (round-6 structure, verified 64 µs): swapped-QK^T
//      32x32 MFMA, in-register softmax, LDS dbuf staged via pre-swizzled
//      global_load_lds source, counted vmcnt(8).
//   4) Wo GEMM 64x128 tiles (512 blocks = 2/CU) -> f32 d_out
// ws (shorts): wb[4x1M] Q[4M] K[4M] VtG[4M] = 32 MB. attn out aliases Q.
// ---------------------------------------------------------------------------

#define DEVI __device__ __forceinline__

typedef __bf16 bf16x8 __attribute__((ext_vector_type(8)));
typedef short  short8 __attribute__((ext_vector_type(8)));
typedef float  f32x4  __attribute__((ext_vector_type(4)));
typedef float  f32x16 __attribute__((ext_vector_type(16)));
typedef unsigned int u32x4 __attribute__((ext_vector_type(4)));

DEVI short f2bfs(float f) {
    __hip_bfloat16 h = __float2bfloat16(f);
    return __builtin_bit_cast(short, h);
}
DEVI unsigned pack2(float a, float b) {
    return (unsigned)(unsigned short)f2bfs(a) | ((unsigned)(unsigned short)f2bfs(b) << 16);
}
DEVI bf16x8 ld8(const short* p) {
    return __builtin_bit_cast(bf16x8, *(const short8*)p);
}
DEVI void gload16(const void* g, void* lds) {
    __builtin_amdgcn_global_load_lds(
        (const __attribute__((address_space(1))) void*)g,
        (__attribute__((address_space(3))) void*)lds, 16, 0, 0);
}
// XOR-swizzled LDS read address for [64][64] bf16 tiles (involution on the
// 16B slot index within each 128B row): byte ^= (row&7)<<4.
DEVI const short* lds_swc(const short* base, int row, int col) {
    return (const short*)((const char*)base + (((row << 7) + (col << 1)) ^ ((row & 7) << 4)));
}

#if defined(__has_builtin)
#if __has_builtin(__builtin_amdgcn_exp2f)
#define HAVE_EXP2 1
#endif
#endif
DEVI float ex2(float x) {
#ifdef HAVE_EXP2
    return __builtin_amdgcn_exp2f(x);
#else
    return __expf(x * 0.69314718055994531f);
#endif
}
// 0.125 (1/sqrt(64)) folded with log2(e): p = 2^((s - m) * CEXP)
#define CEXP 0.18033688011112042f

// ---------------------------------------------------------------------------
// f32 -> bf16 convert.  z=0: x (4M elems) -> xb; z=1..4: W* (1M) -> wb slots.
// ---------------------------------------------------------------------------
__global__ __launch_bounds__(256) void convert_kernel(
    const float* __restrict__ x, const float* __restrict__ Wq,
    const float* __restrict__ Wk, const float* __restrict__ Wv,
    const float* __restrict__ Wo, short* __restrict__ xb, short* __restrict__ wb) {
    const int z = blockIdx.y;
    const float* src;
    short* dst;
    int n;
    if (z == 0) { src = x; dst = xb; n = 4194304; }
    else {
        src = (z == 1) ? Wq : (z == 2) ? Wk : (z == 3) ? Wv : Wo;
        dst = wb + (size_t)(z - 1) * 1048576;
        n = 1048576;
    }
    const int i8 = (blockIdx.x * 256 + threadIdx.x) * 8;
    if (i8 >= n) return;
    float4 a = ((const float4*)(src + i8))[0];
    float4 b = ((const float4*)(src + i8))[1];
    short8 t;
    t[0] = f2bfs(a.x); t[1] = f2bfs(a.y); t[2] = f2bfs(a.z); t[3] = f2bfs(a.w);
    t[4] = f2bfs(b.x); t[5] = f2bfs(b.y); t[6] = f2bfs(b.z); t[7] = f2bfs(b.w);
    *(short8*)(dst + i8) = t;
}

// ---------------------------------------------------------------------------
// bf16 NT-GEMM K-loop, BK=64, XOR-swizzled staging (conflict-free reads).
// Template: <BM, BN, MF, NF, WN>.  4 waves; wm = wid/WN, wn = wid%WN.
// LDS tiles [BM][64] / [BN][64], row-major with byte ^= (row&7)<<4 swizzle,
// achieved via pre-swizzled global SOURCE column (linear gload16 dest).
// ---------------------------------------------------------------------------
template <int BM, int BN, int MF, int NF, int WN>
DEVI void gemm_kloop64(const short* __restrict__ A, const short* __restrict__ B,
                       short* As, short* Bs, int wid, int lane, f32x4 acc[MF][NF]) {
    const int l15 = lane & 15, l4 = lane >> 4;
    const int wm = wid / WN, wn = wid % WN;
    const int rowc = lane >> 3;                 // 0..7: row within 8-row chunk
    const int gcol = ((lane & 7) ^ rowc) * 8;   // pre-swizzled 16B slot
    constexpr int NCHA = BM / 8, NCHB = BN / 8;
#pragma unroll 1
    for (int k0 = 0; k0 < 1024; k0 += 64) {
        __syncthreads();
#pragma unroll
        for (int c = wid; c < NCHA; c += 4)
            gload16(A + (size_t)(c * 8 + rowc) * 1024 + k0 + gcol, As + c * 512);
#pragma unroll
        for (int c = wid; c < NCHB; c += 4)
            gload16(B + (size_t)(c * 8 + rowc) * 1024 + k0 + gcol, Bs + c * 512);
        __syncthreads();
#pragma unroll
        for (int kk = 0; kk < 2; ++kk) {
            bf16x8 af[MF], bf[NF];
#pragma unroll
            for (int m = 0; m < MF; ++m) {
                const int row = wm * (MF * 16) + m * 16 + l15;
                af[m] = ld8(As + row * 64 + (((kk * 4 + l4) ^ (row & 7)) * 8));
            }
#pragma unroll
            for (int n = 0; n < NF; ++n) {
                const int row = wn * (NF * 16) + n * 16 + l15;
                bf[n] = ld8(Bs + row * 64 + (((kk * 4 + l4) ^ (row & 7)) * 8));
            }
#pragma unroll
            for (int m = 0; m < MF; ++m)
#pragma unroll
                for (int n = 0; n < NF; ++n)
                    acc[m][n] = __builtin_amdgcn_mfma_f32_16x16x32_bf16(af[m], bf[n], acc[m][n], 0, 0, 0);
        }
    }
}

// ---------------------------------------------------------------------------
// Fused QKV projection. grid (32, 24): y>>3 selects weight; (y&7) col tile.
// 128x128 tile, BK=64.
// ---------------------------------------------------------------------------
__global__ __launch_bounds__(256) void gemm_qkv_kernel(
    const short* __restrict__ xb, const short* __restrict__ wb,
    short* __restrict__ Qo, short* __restrict__ Ko, short* __restrict__ VtG) {
    __shared__ short As[8192], Bs[8192];
    const int tid = threadIdx.x, lane = tid & 63, wid = tid >> 6;
    const int l15 = lane & 15, l4 = lane >> 4;
    const int wm = wid >> 1, wn = wid & 1;
    const int y = blockIdx.y, wsel = y >> 3;
    const int row0 = blockIdx.x * 128, col0 = (y & 7) * 128;

    f32x4 acc[4][4] = {};
    gemm_kloop64<128, 128, 4, 4, 2>(
        xb + (size_t)row0 * 1024,
        wb + (size_t)wsel * 1048576 + (size_t)col0 * 1024,
        As, Bs, wid, lane, acc);

    if (wsel == 2) {
#pragma unroll
        for (int m = 0; m < 4; ++m)
#pragma unroll
            for (int n = 0; n < 4; ++n)
#pragma unroll
                for (int j = 0; j < 4; ++j) {
                    int row = row0 + wm * 64 + m * 16 + l4 * 4 + j;
                    int col = col0 + wn * 64 + n * 16 + l15;
                    VtG[(size_t)col * 4096 + row] = f2bfs(acc[m][n][j]);
                }
    } else {
        short* C = (wsel == 0) ? Qo : Ko;
#pragma unroll
        for (int m = 0; m < 4; ++m)
#pragma unroll
            for (int n = 0; n < 4; ++n)
#pragma unroll
                for (int j = 0; j < 4; ++j) {
                    int row = row0 + wm * 64 + m * 16 + l4 * 4 + j;
                    int col = col0 + wn * 64 + n * 16 + l15;
                    C[(size_t)row * 1024 + col] = f2bfs(acc[m][n][j]);
                }
    }
}

// ---------------------------------------------------------------------------
// Output projection: 64x128 tile (512 blocks = 2/CU), BK=64. Waves 1x4.
// ---------------------------------------------------------------------------
__global__ __launch_bounds__(256) void gemm_wo_kernel(
    const short* __restrict__ Ao, const short* __restrict__ Wob,
    float* __restrict__ Cout) {
    __shared__ short As[4096], Bs[8192];
    const int tid = threadIdx.x, lane = tid & 63, wid = tid >> 6;
    const int l15 = lane & 15, l4 = lane >> 4;
    const int wn = wid;                       // WN=4: wm = 0
    const int row0 = blockIdx.x * 64, col0 = blockIdx.y * 128;

    f32x4 acc[4][2] = {};
    gemm_kloop64<64, 128, 4, 2, 4>(
        Ao + (size_t)row0 * 1024, Wob + (size_t)col0 * 1024,
        As, Bs, wid, lane, acc);

#pragma unroll
    for (int m = 0; m < 4; ++m)
#pragma unroll
        for (int n = 0; n < 2; ++n)
#pragma unroll
            for (int j = 0; j < 4; ++j) {
                int row = row0 + m * 16 + l4 * 4 + j;
                int col = col0 + wn * 32 + n * 16 + l15;
                Cout[(size_t)row * 1024 + col] = acc[m][n][j];
            }
}

// ---------------------------------------------------------------------------
// One KV tile (verified rounds 4-6): S = K Q^T, exp2-domain online softmax,
// defer-max, shfl_xor(32) P-redistribute, O += P V.
// ---------------------------------------------------------------------------
DEVI void attn_tile(int kv0, bool diag, const short* Ks, const short* Vts,
                    const bf16x8 qf[4], f32x16& o0, f32x16& o1,
                    float& m, float& l, int qrow, int l31, int hi) {
    f32x16 s0 = 0.0f, s1 = 0.0f;
    __builtin_amdgcn_s_setprio(1);
#pragma unroll
    for (int ds = 0; ds < 4; ++ds) {
        bf16x8 kf = ld8(lds_swc(Ks, l31, ds * 16 + hi * 8));
        s0 = __builtin_amdgcn_mfma_f32_32x32x16_bf16(kf, qf[ds], s0, 0, 0, 0);
    }
#pragma unroll
    for (int ds = 0; ds < 4; ++ds) {
        bf16x8 kf = ld8(lds_swc(Ks, 32 + l31, ds * 16 + hi * 8));
        s1 = __builtin_amdgcn_mfma_f32_32x32x16_bf16(kf, qf[ds], s1, 0, 0, 0);
    }
    __builtin_amdgcn_s_setprio(0);

    if (diag) {
#pragma unroll
        for (int r = 0; r < 16; ++r) {
            const int kvr = kv0 + (r & 3) + 8 * (r >> 2) + 4 * hi;
            if (kvr > qrow)      s0[r] = -3.0e38f;
            if (kvr + 32 > qrow) s1[r] = -3.0e38f;
        }
    }
    float mx0 = -3.0e38f, mx1 = -3.0e38f, mx2 = -3.0e38f, mx3 = -3.0e38f;
#pragma unroll
    for (int r = 0; r < 16; r += 4) {
        mx0 = fmaxf(mx0, fmaxf(s0[r],     s1[r]));
        mx1 = fmaxf(mx1, fmaxf(s0[r + 1], s1[r + 1]));
        mx2 = fmaxf(mx2, fmaxf(s0[r + 2], s1[r + 2]));
        mx3 = fmaxf(mx3, fmaxf(s0[r + 3], s1[r + 3]));
    }
    float pmax = fmaxf(fmaxf(mx0, mx1), fmaxf(mx2, mx3));
    pmax = fmaxf(pmax, __shfl_xor(pmax, 32, 64));

    if (__any(pmax > m + 64.0f)) {
        const float mnew = fmaxf(m, pmax);
        const float corr = ex2((m - mnew) * CEXP);
        m = mnew;
        l *= corr;
#pragma unroll
        for (int r = 0; r < 16; ++r) {
            const int cr = (r & 3) + 8 * (r >> 2) + 4 * hi;
            const float c = __shfl(corr, cr, 64);
            o0[r] *= c; o1[r] *= c;
        }
    }

    const float mc = m * CEXP;
    float r0 = 0.f, r1 = 0.f, r2 = 0.f, r3 = 0.f;
    unsigned w0[8], w1[8];
#pragma unroll
    for (int i = 0; i < 8; ++i) {
        const float p0 = ex2(__builtin_fmaf(s0[2 * i],     CEXP, -mc));
        const float p1 = ex2(__builtin_fmaf(s0[2 * i + 1], CEXP, -mc));
        const float p2 = ex2(__builtin_fmaf(s1[2 * i],     CEXP, -mc));
        const float p3 = ex2(__builtin_fmaf(s1[2 * i + 1], CEXP, -mc));
        r0 += p0; r1 += p1; r2 += p2; r3 += p3;
        w0[i] = pack2(p0, p1);
        w1[i] = pack2(p2, p3);
    }
    const float rsum = (r0 + r1) + (r2 + r3);
    l += rsum + __shfl_xor(rsum, 32, 64);

    __builtin_amdgcn_s_setprio(1);
#pragma unroll
    for (int c = 0; c < 2; ++c) {
        const unsigned* w = (c == 0) ? w0 : w1;
        unsigned pw[8];
#pragma unroll
        for (int i = 0; i < 8; ++i) pw[i] = __shfl_xor(w[i], 32, 64);
        u32x4 lo, hw;
        lo[0] = hi ? pw[2] : w[0];  lo[1] = hi ? pw[3] : w[1];
        lo[2] = hi ? w[2]  : pw[0]; lo[3] = hi ? w[3]  : pw[1];
        hw[0] = hi ? pw[6] : w[4];  hw[1] = hi ? pw[7] : w[5];
        hw[2] = hi ? w[6]  : pw[4]; hw[3] = hi ? w[7]  : pw[5];
        const bf16x8 paL = __builtin_bit_cast(bf16x8, lo);
        const bf16x8 paH = __builtin_bit_cast(bf16x8, hw);

        bf16x8 vb;
        vb = ld8(lds_swc(Vts, l31,      c * 32 + hi * 8));
        o0 = __builtin_amdgcn_mfma_f32_32x32x16_bf16(paL, vb, o0, 0, 0, 0);
        vb = ld8(lds_swc(Vts, 32 + l31, c * 32 + hi * 8));
        o1 = __builtin_amdgcn_mfma_f32_32x32x16_bf16(paL, vb, o1, 0, 0, 0);
        vb = ld8(lds_swc(Vts, l31,      c * 32 + 16 + hi * 8));
        o0 = __builtin_amdgcn_mfma_f32_32x32x16_bf16(paH, vb, o0, 0, 0, 0);
        vb = ld8(lds_swc(Vts, 32 + l31, c * 32 + 16 + hi * 8));
        o1 = __builtin_amdgcn_mfma_f32_32x32x16_bf16(paH, vb, o1, 0, 0, 0);
    }
    __builtin_amdgcn_s_setprio(0);
}

// ---------------------------------------------------------------------------
// Causal flash attention (round-6 structure, verified). grid 1024
// (heavy-first: qt = 31 - bid/32), block 128 = 2 warps x 32 q-rows, KV 64.
// Staging via global_load_lds w/ pre-swizzled global source; double-buffered,
// counted vmcnt(8): tile t+1's loads fly during compute(t).
// ---------------------------------------------------------------------------
__global__ __launch_bounds__(128) void attn_kernel(
    const short* __restrict__ Q, const short* __restrict__ K,
    const short* __restrict__ VtG, short* __restrict__ O) {
    __shared__ short KsA[4096], VtsA[4096], KsB[4096], VtsB[4096];

    const int tid = threadIdx.x, lane = tid & 63, wid = tid >> 6;
    const int l31 = lane & 31, hi = lane >> 5;
    const int bid = blockIdx.x;
    const int qt = 31 - (bid >> 5);
    const int bh = bid & 31;
    const int b = bh >> 4, h = bh & 15;
    const size_t base = (size_t)b * 2048 * 1024 + (size_t)h * 64;
    const short* Qp = Q + base;
    const short* Kp = K + base;
    const short* Vp = VtG + (size_t)(h * 64) * 4096 + (size_t)b * 2048;
    short* Op = O + base;

    const int q0w = qt * 64 + wid * 32;
    const int qrow = q0w + l31;

    const int srw = lane >> 3;                 // 0..7
    const int swc = ((lane & 7) ^ srw) * 8;    // swizzled col (elements)
    const short* kSrc = Kp + (size_t)srw * 1024 + swc;
    const short* vSrc = Vp + (size_t)srw * 4096 + swc;
    const int cc0 = wid * 4;

#define ISSUE_TILE(Ksb, Vtsb, kv0_)                                           \
    {                                                                         \
        const int kv0i = (kv0_);                                              \
        _Pragma("unroll")                                                     \
        for (int c = 0; c < 4; ++c) {                                         \
            const int cc = cc0 + c;                                           \
            gload16(kSrc + (size_t)(kv0i + cc * 8) * 1024, (Ksb) + cc * 512); \
            gload16(vSrc + (size_t)(cc * 8) * 4096 + kv0i, (Vtsb) + cc * 512);\
        }                                                                     \
    }

    ISSUE_TILE(KsA, VtsA, 0);

    bf16x8 qf[4];
#pragma unroll
    for (int ds = 0; ds < 4; ++ds)
        qf[ds] = ld8(Qp + (size_t)qrow * 1024 + ds * 16 + hi * 8);

    f32x16 o0 = 0.0f, o1 = 0.0f;
    float m = -INFINITY, l = 0.0f;
    const int ntiles = qt + 1;

#pragma unroll 1
    for (int t = 0; t < ntiles; ++t) {
        const short* Ks  = (t & 1) ? KsB  : KsA;
        const short* Vts = (t & 1) ? VtsB : VtsA;
        if (t + 1 < ntiles) {
            short* Ksn  = (t & 1) ? KsA  : KsB;
            short* Vtsn = (t & 1) ? VtsA : VtsB;
            ISSUE_TILE(Ksn, Vtsn, (t + 1) * 64);
            asm volatile("s_waitcnt vmcnt(8)" ::: "memory");
        } else {
            asm volatile("s_waitcnt vmcnt(0)" ::: "memory");
        }
        __builtin_amdgcn_s_barrier();
        __builtin_amdgcn_sched_barrier(0);
        attn_tile(t * 64, (t * 64 + 63 > q0w), Ks, Vts, qf, o0, o1, m, l, qrow, l31, hi);
        __builtin_amdgcn_s_barrier();
    }
#undef ISSUE_TILE

    const float il = 1.0f / l;
#pragma unroll
    for (int r = 0; r < 16; ++r) {
        const int cr = (r & 3) + 8 * (r >> 2) + 4 * hi;
        const float s = __shfl(il, cr, 64);
        const size_t row = (size_t)(q0w + cr) * 1024;
        Op[row + l31]      = f2bfs(o0[r] * s);
        Op[row + 32 + l31] = f2bfs(o1[r] * s);
    }
}

// ---------------------------------------------------------------------------
extern "C" void kernel_launch(void* const* d_in, const int* in_sizes, int n_in,
                              void* d_out, int out_size, void* d_ws, size_t ws_size,
                              hipStream_t stream) {
    const float* x  = (const float*)d_in[0];
    const float* Wq = (const float*)d_in[1];
    const float* Wk = (const float*)d_in[2];
    const float* Wv = (const float*)d_in[3];
    const float* Wo = (const float*)d_in[4];

    short* wb  = (short*)d_ws;                 // 4 x 1M shorts (8 MB)
    short* Qw  = wb + (size_t)4 * 1048576;     // 8 MB (attn out aliases this)
    short* Kw  = Qw + (size_t)4194304;         // 8 MB
    short* Vtw = Kw + (size_t)4194304;         // 8 MB  (VtG[1024][4096])
    short* xb  = (short*)d_out;                // bf16 x lives in d_out[0:8MB]

    convert_kernel<<<dim3(2048, 5), 256, 0, stream>>>(x, Wq, Wk, Wv, Wo, xb, wb);
    gemm_qkv_kernel<<<dim3(32, 24), 256, 0, stream>>>(xb, wb, Qw, Kw, Vtw);
    attn_kernel<<<1024, 128, 0, stream>>>(Qw, Kw, Vtw, Qw);
    gemm_wo_kernel<<<dim3(64, 8), 256, 0, stream>>>(Qw, wb + (size_t)3 * 1048576, (float*)d_out);
}